// Round 13
// baseline (130.779 us; speedup 1.0000x reference)
//
#include <hip/hip_runtime.h>
#include <stdio.h>

// Sizes fixed by the reference
#define H 4
#define B 8192
#define F 64
#define ALPHA 0.2f
#define NB 4096
#define DMIN (-8.0f)
#define DSCALE 256.0f    // NB / 16 over [-8, 8); clamp keeps monotonicity -> exact
#define NPART 16         // privatized histogram partials per head
#define BSLD 132         // BS row: 64 (e^d*hp) + 64 (e^.2d*hp) + 2 scalar sums

__device__ __forceinline__ int bucket_of(float x)
{
  int b = (int)((x - DMIN) * DSCALE);   // monotone non-decreasing in x
  return min(max(b, 0), NB - 1);
}

// -------------------------------------------------------------------------
// K1: h_prime = h @ w per head; s = hp.a_src, d = hp.a_dst. (proven R8)
__global__ __launch_bounds__(256) void k_hprime(
    const float* __restrict__ h, const float* __restrict__ w,
    const float* __restrict__ a_src, const float* __restrict__ a_dst,
    float* __restrict__ hp, float* __restrict__ s, float* __restrict__ d)
{
  int head = blockIdx.y;
  int row0 = blockIdx.x * 64;
  __shared__ float wl[F * F];
  __shared__ float hl[64 * F];
  const float4* wsrc = (const float4*)(w + (size_t)head * F * F);
  const float4* hsrc = (const float4*)(h + (size_t)row0 * F);
  float4* wl4 = (float4*)wl;
  float4* hl4 = (float4*)hl;
  for (int t = threadIdx.x; t < F * F / 4; t += 256) { wl4[t] = wsrc[t]; hl4[t] = hsrc[t]; }
  __syncthreads();
  int o  = threadIdx.x & 63;
  int rb = threadIdx.x >> 6;
  float as = a_src[head * F + o];
  float ad = a_dst[head * F + o];
  float acc[16];
#pragma unroll
  for (int rg = 0; rg < 16; ++rg) acc[rg] = 0.f;
#pragma unroll 4
  for (int i4 = 0; i4 < F / 4; ++i4) {
    float w0 = wl[(4 * i4 + 0) * F + o];
    float w1 = wl[(4 * i4 + 1) * F + o];
    float w2 = wl[(4 * i4 + 2) * F + o];
    float w3 = wl[(4 * i4 + 3) * F + o];
#pragma unroll
    for (int rg = 0; rg < 16; ++rg) {
      float4 h4 = *((const float4*)(hl + (rg * 4 + rb) * F) + i4);
      acc[rg] = fmaf(h4.x, w0, fmaf(h4.y, w1, fmaf(h4.z, w2, fmaf(h4.w, w3, acc[rg]))));
    }
  }
#pragma unroll
  for (int rg = 0; rg < 16; ++rg) {
    int r = row0 + rg * 4 + rb;
    hp[((size_t)head * B + r) * F + o] = acc[rg];
    float vs = acc[rg] * as, vd = acc[rg] * ad;
#pragma unroll
    for (int off = 32; off; off >>= 1) { vs += __shfl_down(vs, off); vd += __shfl_down(vd, off); }
    if (o == 0) {
      s[(size_t)head * B + r] = vs;
      d[(size_t)head * B + r] = vd;
    }
  }
}

// -------------------------------------------------------------------------
// K2: privatized histogram of d (events only): 16 blocks/head, own LDS hist.
__global__ __launch_bounds__(256) void k_hist(
    const float* __restrict__ d, int* __restrict__ phist)
{
  int head = blockIdx.y, part = blockIdx.x;    // part 0..NPART-1
  int tid = threadIdx.x;
  __shared__ int hist[NB];                     // 16 KB
#pragma unroll
  for (int t = 0; t < NB / 256; ++t) hist[tid + t * 256] = 0;
  __syncthreads();
  int g0 = part * (B / NPART);                 // 512 elements per part
#pragma unroll
  for (int t = 0; t < (B / NPART) / 256; ++t) {
    int g = g0 + t * 256 + tid;
    atomicAdd(&hist[bucket_of(d[(size_t)head * B + g])], 1);
  }
  __syncthreads();
  int* ph = phist + ((size_t)head * NPART + part) * NB;
#pragma unroll
  for (int t = 0; t < NB / 256; ++t) ph[tid + t * 256] = hist[tid + t * 256];
}

// -------------------------------------------------------------------------
// K3: per-head scan: sum 16 partials, exclusive scan (proven tail).
__global__ __launch_bounds__(1024) void k_scan(
    const int* __restrict__ phist, int* __restrict__ bstart, int* __restrict__ gcur)
{
  int head = blockIdx.x;
  int tid = threadIdx.x;
  __shared__ int wtot[16], woff[16];
  int h0 = 0, h1 = 0, h2 = 0, h3 = 0;
  const int* ph = phist + (size_t)head * NPART * NB + 4 * tid;
#pragma unroll
  for (int p = 0; p < NPART; ++p) {
    h0 += ph[0]; h1 += ph[1]; h2 += ph[2]; h3 += ph[3];
    ph += NB;
  }
  int sum = h0 + h1 + h2 + h3;
  int lane = tid & 63, wid = tid >> 6;
  int run = sum;
#pragma unroll
  for (int off = 1; off < 64; off <<= 1) {
    int u = __shfl_up(run, off);
    if (lane >= off) run += u;
  }
  if (lane == 63) wtot[wid] = run;
  __syncthreads();
  if (tid < 16) {
    int off = 0;
    for (int j = 0; j < tid; ++j) off += wtot[j];
    woff[tid] = off;
  }
  __syncthreads();
  int excl = woff[wid] + run - sum;
  int bb = head * (NB + 1) + 4 * tid;
  int gb = head * NB + 4 * tid;
  int e0 = excl, e1 = e0 + h0, e2 = e1 + h1, e3 = e2 + h2;
  bstart[bb] = e0; bstart[bb + 1] = e1; bstart[bb + 2] = e2; bstart[bb + 3] = e3;
  gcur[gb] = e0; gcur[gb + 1] = e1; gcur[gb + 2] = e2; gcur[gb + 3] = e3;
  if (tid == 1023) bstart[head * (NB + 1) + NB] = e3 + h3;   // == B
}

// -------------------------------------------------------------------------
// K4: bucket scatter; ALSO precompute e^d, e^{0.2 d} at the scattered slot
// (so no kernel downstream ever does expf inside a data-dependent loop).
__global__ __launch_bounds__(256) void k_scatter(
    const float* __restrict__ d, int* __restrict__ gcur,
    float* __restrict__ ds, int* __restrict__ is,
    float* __restrict__ e1a, float* __restrict__ e2a)
{
  int head = blockIdx.y;
  int i = blockIdx.x * 256 + threadIdx.x;     // 0..B-1
  float v = d[(size_t)head * B + i];
  int b = bucket_of(v);
  int pos = atomicAdd(&gcur[head * NB + b], 1);
  size_t gp = (size_t)head * B + pos;
  ds[gp] = v;
  is[gp] = i;
  e1a[gp] = expf(v);
  e2a[gp] = expf(ALPHA * v);
}

// -------------------------------------------------------------------------
// K5: per-bucket sums (one wave per bucket; ~2 avg, ~13 max elements).
__global__ __launch_bounds__(256) void k_bsum(
    const float* __restrict__ e1a, const float* __restrict__ e2a,
    const int* __restrict__ is, const float* __restrict__ hp,
    const int* __restrict__ bstart, float* __restrict__ BS)
{
  int head = blockIdx.y;
  int b = blockIdx.x * 4 + (threadIdx.x >> 6);
  int o = threadIdx.x & 63;
  int k0 = bstart[head * (NB + 1) + b];
  int k1 = bstart[head * (NB + 1) + b + 1];
  const float* e1h = e1a + (size_t)head * B;
  const float* e2h = e2a + (size_t)head * B;
  const int*   ish = is + (size_t)head * B;
  const float* hph = hp + (size_t)head * B * F;
  float a1 = 0.f, a2 = 0.f, s1 = 0.f, s2 = 0.f;
  for (int k = k0; k < k1; ++k) {
    float e1 = e1h[k], e2 = e2h[k];              // wave-uniform loads
    float hv = hph[(size_t)ish[k] * F + o];      // coalesced 256B gather
    a1 = fmaf(e1, hv, a1); a2 = fmaf(e2, hv, a2);
    s1 += e1; s2 += e2;
  }
  float* row = BS + ((size_t)head * NB + b) * BSLD;
  row[o] = a1; row[64 + o] = a2;
  if (o == 0) { row[128] = s1; row[129] = s2; }
}

// -------------------------------------------------------------------------
// K6: in-place exclusive prefix over NB buckets per (head, channel).
// Register-resident: 64 independent loads, in-reg scan, shuffle, 64 stores.
__global__ __launch_bounds__(64) void k_bscan(
    float* __restrict__ BS, float* __restrict__ totals)
{
  int head = blockIdx.y;
  int c = blockIdx.x;       // 0..129
  int lane = threadIdx.x;
  float* base = BS + (size_t)head * NB * BSLD + c;
  int b0 = lane * 64;
  float v[64];
#pragma unroll
  for (int t = 0; t < 64; ++t) v[t] = base[(size_t)(b0 + t) * BSLD];
  float sum = 0.f;
#pragma unroll
  for (int t = 0; t < 64; ++t) { sum += v[t]; v[t] = sum; }  // inclusive chunk prefix
  float run = sum;
#pragma unroll
  for (int off = 1; off < 64; off <<= 1) {
    float u = __shfl_up(run, off);
    if (lane >= off) run += u;
  }
  float excl = run - sum;
  if (lane == 63) totals[head * BSLD + c] = run;
#pragma unroll
  for (int t = 0; t < 64; ++t)
    base[(size_t)(b0 + t) * BSLD] = excl + (t == 0 ? 0.f : v[t - 1]);
}

// -------------------------------------------------------------------------
// K7: per row i: bucket-prefix lookup + exact boundary correction
// (no expf in the loop: e1/e2 precomputed; ~13 gather+FMA iterations).
__global__ __launch_bounds__(256) void k_out(
    const float* __restrict__ s, const float* __restrict__ ds,
    const int* __restrict__ is, const float* __restrict__ e1a,
    const float* __restrict__ e2a, const float* __restrict__ hp,
    const float* __restrict__ BS, const float* __restrict__ totals,
    const int* __restrict__ bstart, const float* __restrict__ bias,
    float* __restrict__ out)
{
  int head = blockIdx.y;
  int i = blockIdx.x * 4 + (threadIdx.x >> 6);
  int o = threadIdx.x & 63;
  float si = s[(size_t)head * B + i];
  float t = -si;
  int q = bucket_of(t);
  int k0 = bstart[head * (NB + 1) + q];
  int k1 = bstart[head * (NB + 1) + q + 1];
  const float* dsh = ds + (size_t)head * B;
  const int*   ish = is + (size_t)head * B;
  const float* e1h = e1a + (size_t)head * B;
  const float* e2h = e2a + (size_t)head * B;
  const float* hph = hp + (size_t)head * B * F;

  // exact partial sums over the boundary bucket (elements with d < t)
  float pl1 = 0.f, pl2 = 0.f, pl1s = 0.f, pl2s = 0.f;
  for (int k = k0; k < k1; ++k) {
    float dv = dsh[k];                           // wave-uniform
    if (dv < t) {
      float e1 = e1h[k], e2 = e2h[k];
      float hv = hph[(size_t)ish[k] * F + o];
      pl1 = fmaf(e1, hv, pl1);
      pl2 = fmaf(e2, hv, pl2);
      pl1s += e1; pl2s += e2;
    }
  }

  const float* row = BS + ((size_t)head * NB + q) * BSLD;
  float pe1 = row[o], pe2 = row[64 + o];
  float p1  = row[128], p2 = row[129];
  float e1s = expf(si), e2s = expf(ALPHA * si);
  float T1  = totals[head * BSLD + 128];
  float TE1 = totals[head * BSLD + o];
  float denom = e2s * (p2 + pl2s) + e1s * (T1 - p1 - pl1s);
  float num   = e2s * (pe2 + pl2) + e1s * (TE1 - pe1 - pl1);
  out[(size_t)i * (H * F) + head * F + o] = num / denom + bias[o];
}

// -------------------------------------------------------------------------
extern "C" void kernel_launch(void* const* d_in, const int* in_sizes, int n_in,
                              void* d_out, int out_size, void* d_ws, size_t ws_size,
                              hipStream_t stream)
{
  const float* h     = (const float*)d_in[0];
  const float* w     = (const float*)d_in[1];
  const float* a_src = (const float*)d_in[2];
  const float* a_dst = (const float*)d_in[3];
  const float* bias  = (const float*)d_in[4];
  float* out = (float*)d_out;

  float* p = (float*)d_ws;
  float* hp     = p; p += (size_t)H * B * F;        // 8.4 MB
  float* s      = p; p += H * B;
  float* dd     = p; p += H * B;
  float* dsort  = p; p += H * B;
  int*   isort  = (int*)p; p += H * B;
  float* e1a    = p; p += H * B;
  float* e2a    = p; p += H * B;
  float* BS     = p; p += (size_t)H * NB * BSLD;    // 8.7 MB
  float* totals = p; p += H * BSLD;
  int* phist    = (int*)p; p += (size_t)H * NPART * NB;  // 1 MB
  int* bstart   = (int*)p; p += H * (NB + 1);
  int* gcur     = (int*)p; p += H * NB;

  size_t need = (size_t)((char*)p - (char*)d_ws);
  if (ws_size < need) {
    fprintf(stderr, "kernel_launch: ws_size %zu < needed %zu\n", ws_size, need);
    return;
  }

  k_hprime<<<dim3(B / 64, H), 256, 0, stream>>>(h, w, a_src, a_dst, hp, s, dd);
  k_hist<<<dim3(NPART, H), 256, 0, stream>>>(dd, phist);
  k_scan<<<H, 1024, 0, stream>>>(phist, bstart, gcur);
  k_scatter<<<dim3(B / 256, H), 256, 0, stream>>>(dd, gcur, dsort, isort, e1a, e2a);
  k_bsum<<<dim3(NB / 4, H), 256, 0, stream>>>(e1a, e2a, isort, hp, bstart, BS);
  k_bscan<<<dim3(130, H), 64, 0, stream>>>(BS, totals);
  k_out<<<dim3(B / 4, H), 256, 0, stream>>>(s, dsort, isort, e1a, e2a, hp, BS, totals, bstart, bias, out);
}

// Round 14
// 74.420 us; speedup vs baseline: 1.7573x; 1.7573x over previous
//
#include <hip/hip_runtime.h>
#include <stdio.h>

// Sizes fixed by the reference
#define H 4
#define B 8192
#define M2 (2 * B)       // merged stream: B queries (t=-s) + B events (d)
#define F 64
#define ALPHA 0.2f
#define NB 8192
#define DMIN (-8.0f)
#define DSCALE 512.0f    // NB / 16 over [-8, 8); clamp keeps monotonicity -> exact
#define TSZ 16
#define NTL2 (M2 / TSZ)  // 1024 tiles per head
#define PELD 132         // row: 64 (e^d*hp) + 64 (e^.2d*hp) + 2 scalar prefixes

__device__ __forceinline__ int bucket_of(float x)
{
  int b = (int)((x - DMIN) * DSCALE);   // monotone non-decreasing in x
  return min(max(b, 0), NB - 1);
}

// -------------------------------------------------------------------------
// K1: h_prime = h @ w per head; s = hp.a_src, d = hp.a_dst. (proven R8)
__global__ __launch_bounds__(256) void k_hprime(
    const float* __restrict__ h, const float* __restrict__ w,
    const float* __restrict__ a_src, const float* __restrict__ a_dst,
    float* __restrict__ hp, float* __restrict__ s, float* __restrict__ d)
{
  int head = blockIdx.y;
  int row0 = blockIdx.x * 64;
  __shared__ float wl[F * F];
  __shared__ float hl[64 * F];
  const float4* wsrc = (const float4*)(w + (size_t)head * F * F);
  const float4* hsrc = (const float4*)(h + (size_t)row0 * F);
  float4* wl4 = (float4*)wl;
  float4* hl4 = (float4*)hl;
  for (int t = threadIdx.x; t < F * F / 4; t += 256) { wl4[t] = wsrc[t]; hl4[t] = hsrc[t]; }
  __syncthreads();
  int o  = threadIdx.x & 63;
  int rb = threadIdx.x >> 6;
  float as = a_src[head * F + o];
  float ad = a_dst[head * F + o];
  float acc[16];
#pragma unroll
  for (int rg = 0; rg < 16; ++rg) acc[rg] = 0.f;
#pragma unroll 4
  for (int i4 = 0; i4 < F / 4; ++i4) {
    float w0 = wl[(4 * i4 + 0) * F + o];
    float w1 = wl[(4 * i4 + 1) * F + o];
    float w2 = wl[(4 * i4 + 2) * F + o];
    float w3 = wl[(4 * i4 + 3) * F + o];
#pragma unroll
    for (int rg = 0; rg < 16; ++rg) {
      float4 h4 = *((const float4*)(hl + (rg * 4 + rb) * F) + i4);
      acc[rg] = fmaf(h4.x, w0, fmaf(h4.y, w1, fmaf(h4.z, w2, fmaf(h4.w, w3, acc[rg]))));
    }
  }
#pragma unroll
  for (int rg = 0; rg < 16; ++rg) {
    int r = row0 + rg * 4 + rb;
    hp[((size_t)head * B + r) * F + o] = acc[rg];
    float vs = acc[rg] * as, vd = acc[rg] * ad;
#pragma unroll
    for (int off = 32; off; off >>= 1) { vs += __shfl_down(vs, off); vd += __shfl_down(vd, off); }
    if (o == 0) {
      s[(size_t)head * B + r] = vs;
      d[(size_t)head * B + r] = vd;
    }
  }
}

// -------------------------------------------------------------------------
// K2: per head (1 block of 1024): 32KB LDS histogram of the merged stream ->
// exclusive scan (8 buckets/thread) -> bstart + scatter cursors.
__global__ __launch_bounds__(1024) void k_hist_scan(
    const float* __restrict__ s, const float* __restrict__ d,
    int* __restrict__ bstart, int* __restrict__ gcur)
{
  int head = blockIdx.x;
  int tid = threadIdx.x;
  __shared__ int hist[NB];          // 32 KB
  __shared__ int wtot[16], woff[16];
#pragma unroll
  for (int t = 0; t < NB / 1024; ++t) hist[tid + t * 1024] = 0;
  __syncthreads();
  const float* sh = s + (size_t)head * B;
  const float* dh = d + (size_t)head * B;
#pragma unroll
  for (int t = 0; t < B / 1024; ++t)
    atomicAdd(&hist[bucket_of(-sh[tid + t * 1024])], 1);
#pragma unroll
  for (int t = 0; t < B / 1024; ++t)
    atomicAdd(&hist[bucket_of(dh[tid + t * 1024])], 1);
  __syncthreads();
  int v[8];
#pragma unroll
  for (int t = 0; t < 8; ++t) v[t] = hist[tid * 8 + t];
  int sum = 0;
#pragma unroll
  for (int t = 0; t < 8; ++t) { sum += v[t]; v[t] = sum; }   // inclusive
  int lane = tid & 63, wid = tid >> 6;
  int run = sum;
#pragma unroll
  for (int off = 1; off < 64; off <<= 1) {
    int u = __shfl_up(run, off);
    if (lane >= off) run += u;
  }
  if (lane == 63) wtot[wid] = run;
  __syncthreads();
  if (tid < 16) {
    int off = 0;
    for (int j = 0; j < tid; ++j) off += wtot[j];
    woff[tid] = off;
  }
  __syncthreads();
  int excl = woff[wid] + run - sum;
  int bb = head * (NB + 1) + tid * 8;
  int gb = head * NB + tid * 8;
#pragma unroll
  for (int t = 0; t < 8; ++t) {
    int e = excl + (t == 0 ? 0 : v[t - 1]);
    bstart[bb + t] = e;
    gcur[gb + t] = e;
  }
  if (tid == 1023) bstart[head * (NB + 1) + NB] = excl + v[7];   // == M2
}

// -------------------------------------------------------------------------
// K3: bucket scatter of the merged stream. id g: [0,B) query i (v=-s_i),
// [B,2B) event j=g-B (v=d_j). Order within bucket arbitrary; k_sort fixes it.
__global__ __launch_bounds__(256) void k_scatter(
    const float* __restrict__ s, const float* __restrict__ d, int* __restrict__ gcur,
    float* __restrict__ vsort, int* __restrict__ gsort)
{
  int head = blockIdx.y;
  int g = blockIdx.x * 256 + threadIdx.x;     // 0..M2-1
  float v = (g < B) ? -s[(size_t)head * B + g] : d[(size_t)head * B + (g - B)];
  int b = bucket_of(v);
  int pos = atomicAdd(&gcur[head * NB + b], 1);
  vsort[(size_t)head * M2 + pos] = v;
  gsort[(size_t)head * M2 + pos] = g;
}

// -------------------------------------------------------------------------
// K4: exact rank sort within each bucket (~12 central max at NB=8192).
// Strict total order (v, g): at equal v the query (g<B) precedes the event
// (g>=B) -> prefix at a query excludes events with d == t, matching `d < t`.
__global__ __launch_bounds__(256) void k_sort(
    const float* __restrict__ vsort, const int* __restrict__ gsort,
    const int* __restrict__ bstart, float* __restrict__ vs2, int* __restrict__ gs2)
{
  int head = blockIdx.y;
  int b = blockIdx.x * 4 + (threadIdx.x >> 6);
  int lane = threadIdx.x & 63;
  int k0 = bstart[head * (NB + 1) + b];
  int k1 = bstart[head * (NB + 1) + b + 1];
  const float* vh = vsort + (size_t)head * M2;
  const int*   gh = gsort + (size_t)head * M2;
  for (int e = k0 + lane; e < k1; e += 64) {
    float vv = vh[e]; int gv = gh[e];
    int rank = 0;
    for (int k = k0; k < k1; ++k) {        // wave-uniform broadcast loads
      float v2 = vh[k]; int g2 = gh[k];
      rank += (v2 < vv) || (v2 == vv && g2 < gv);
    }
    vs2[(size_t)head * M2 + k0 + rank] = vv;
    gs2[(size_t)head * M2 + k0 + rank] = gv;
  }
}

// -------------------------------------------------------------------------
// K5a: per-tile sums over the merged order; queries contribute zero.
__global__ __launch_bounds__(256) void k_peA(
    const float* __restrict__ vs2, const int* __restrict__ gs2,
    const float* __restrict__ hp, float* __restrict__ TS)
{
  int head = blockIdx.y;
  int tile = blockIdx.x * 4 + (threadIdx.x >> 6);
  int o = threadIdx.x & 63;
  int k0 = tile * TSZ;
  const float* vsh = vs2 + (size_t)head * M2;
  const int*   gsh = gs2 + (size_t)head * M2;
  const float* hph = hp + (size_t)head * B * F;
  float vv[TSZ]; int gg[TSZ];
#pragma unroll
  for (int j = 0; j < TSZ; ++j) { vv[j] = vsh[k0 + j]; gg[j] = gsh[k0 + j]; }
  float hv[TSZ], e1[TSZ], e2[TSZ];
#pragma unroll
  for (int j = 0; j < TSZ; ++j)
    hv[j] = (gg[j] >= B) ? hph[(size_t)(gg[j] - B) * F + o] : 0.f;
#pragma unroll
  for (int j = 0; j < TSZ; ++j) {
    e1[j] = (gg[j] >= B) ? expf(vv[j]) : 0.f;
    e2[j] = (gg[j] >= B) ? expf(ALPHA * vv[j]) : 0.f;
  }
  float a1 = 0.f, a2 = 0.f, s1 = 0.f, s2 = 0.f;
#pragma unroll
  for (int j = 0; j < TSZ; ++j) {
    a1 = fmaf(e1[j], hv[j], a1);
    a2 = fmaf(e2[j], hv[j], a2);
    s1 += e1[j]; s2 += e2[j];
  }
  float* row = TS + ((size_t)head * NTL2 + tile) * PELD;
  row[o] = a1; row[64 + o] = a2;
  if (o == 0) { row[128] = s1; row[129] = s2; }
}

// K5b: exclusive scan of 1024 tile sums per (head, channel) — WIDENED:
// 4-wave blocks (wave w owns tile quarter, lane owns 4 tiles) -> 2080 waves
// of latency-hiding instead of 520 (R13 lesson: column-strided scans are
// latency-bound; parallelism is the fix).
__global__ __launch_bounds__(256) void k_peB(
    float* __restrict__ TS, float* __restrict__ totals)
{
  int head = blockIdx.y;
  int c = blockIdx.x;       // 0..129
  int lane = threadIdx.x & 63, wv = threadIdx.x >> 6;
  __shared__ float wtot[4];
  float* base = TS + (size_t)head * NTL2 * PELD + c;
  int t0 = (wv * 64 + lane) * 4;
  float v[4];
#pragma unroll
  for (int t = 0; t < 4; ++t) v[t] = base[(size_t)(t0 + t) * PELD];
  float sum = 0.f;
#pragma unroll
  for (int t = 0; t < 4; ++t) { sum += v[t]; v[t] = sum; }  // inclusive chunk prefix
  float run = sum;
#pragma unroll
  for (int off = 1; off < 64; off <<= 1) {
    float u = __shfl_up(run, off);
    if (lane >= off) run += u;
  }
  if (lane == 63) wtot[wv] = run;
  __syncthreads();
  float woff = 0.f;
  for (int j = 0; j < wv; ++j) woff += wtot[j];
  float excl = woff + run - sum;
  if (wv == 3 && lane == 63) totals[head * PELD + c] = woff + run;
#pragma unroll
  for (int t = 0; t < 4; ++t)
    base[(size_t)(t0 + t) * PELD] = excl + (t == 0 ? 0.f : v[t - 1]);
}

// K5c: replay tiles with running prefix; EMIT OUTPUT at each query element.
__global__ __launch_bounds__(256) void k_peC_out(
    const float* __restrict__ vs2, const int* __restrict__ gs2,
    const float* __restrict__ hp, const float* __restrict__ TS,
    const float* __restrict__ totals, const float* __restrict__ bias,
    float* __restrict__ out)
{
  int head = blockIdx.y;
  int tile = blockIdx.x * 4 + (threadIdx.x >> 6);
  int o = threadIdx.x & 63;
  int k0 = tile * TSZ;
  const float* vsh = vs2 + (size_t)head * M2;
  const int*   gsh = gs2 + (size_t)head * M2;
  const float* hph = hp + (size_t)head * B * F;
  float vv[TSZ]; int gg[TSZ];
#pragma unroll
  for (int j = 0; j < TSZ; ++j) { vv[j] = vsh[k0 + j]; gg[j] = gsh[k0 + j]; }
  float hv[TSZ], e1[TSZ], e2[TSZ];
#pragma unroll
  for (int j = 0; j < TSZ; ++j)
    hv[j] = (gg[j] >= B) ? hph[(size_t)(gg[j] - B) * F + o] : 0.f;
#pragma unroll
  for (int j = 0; j < TSZ; ++j) {
    e1[j] = (gg[j] >= B) ? expf(vv[j]) : 0.f;
    e2[j] = (gg[j] >= B) ? expf(ALPHA * vv[j]) : 0.f;
  }
  const float* trow = TS + ((size_t)head * NTL2 + tile) * PELD;
  float a1 = trow[o], a2 = trow[64 + o], s1 = trow[128], s2 = trow[129];
  float TE1 = totals[head * PELD + o];
  float T1  = totals[head * PELD + 128];
  float bo  = bias[o];
#pragma unroll
  for (int j = 0; j < TSZ; ++j) {
    if (gg[j] < B) {                       // query: emit output row (wave-uniform)
      int i = gg[j];
      float si = -vv[j];
      float e1f = expf(si), e2f = expf(ALPHA * si);
      float denom = e2f * s2 + e1f * (T1 - s1);
      float num   = e2f * a2 + e1f * (TE1 - a1);
      out[(size_t)i * (H * F) + head * F + o] = num / denom + bo;
    } else {                               // event: accumulate prefix
      a1 = fmaf(e1[j], hv[j], a1);
      a2 = fmaf(e2[j], hv[j], a2);
      s1 += e1[j]; s2 += e2[j];
    }
  }
}

// -------------------------------------------------------------------------
extern "C" void kernel_launch(void* const* d_in, const int* in_sizes, int n_in,
                              void* d_out, int out_size, void* d_ws, size_t ws_size,
                              hipStream_t stream)
{
  const float* h     = (const float*)d_in[0];
  const float* w     = (const float*)d_in[1];
  const float* a_src = (const float*)d_in[2];
  const float* a_dst = (const float*)d_in[3];
  const float* bias  = (const float*)d_in[4];
  float* out = (float*)d_out;

  float* p = (float*)d_ws;
  float* hp     = p; p += (size_t)H * B * F;        // 8.4 MB
  float* s      = p; p += H * B;
  float* dd     = p; p += H * B;
  float* vsort  = p; p += (size_t)H * M2;
  int*   gsort  = (int*)p; p += (size_t)H * M2;
  float* vs2    = p; p += (size_t)H * M2;
  int*   gs2    = (int*)p; p += (size_t)H * M2;
  float* TS     = p; p += (size_t)H * NTL2 * PELD;  // 2.2 MB
  float* totals = p; p += H * PELD;
  int* bstart   = (int*)p; p += H * (NB + 1);
  int* gcur     = (int*)p; p += H * NB;

  size_t need = (size_t)((char*)p - (char*)d_ws);
  if (ws_size < need) {
    fprintf(stderr, "kernel_launch: ws_size %zu < needed %zu\n", ws_size, need);
    return;
  }

  k_hprime<<<dim3(B / 64, H), 256, 0, stream>>>(h, w, a_src, a_dst, hp, s, dd);
  k_hist_scan<<<H, 1024, 0, stream>>>(s, dd, bstart, gcur);
  k_scatter<<<dim3(M2 / 256, H), 256, 0, stream>>>(s, dd, gcur, vsort, gsort);
  k_sort<<<dim3(NB / 4, H), 256, 0, stream>>>(vsort, gsort, bstart, vs2, gs2);
  k_peA<<<dim3(NTL2 / 4, H), 256, 0, stream>>>(vs2, gs2, hp, TS);
  k_peB<<<dim3(130, H), 256, 0, stream>>>(TS, totals);
  k_peC_out<<<dim3(NTL2 / 4, H), 256, 0, stream>>>(vs2, gs2, hp, TS, totals, bias, out);
}